// Round 22
// baseline (58.542 us; speedup 1.0000x reference)
//
#include <hip/hip_runtime.h>

#define NB    8
#define NH    16384
#define NL    2048
#define F_HR  64
#define F_LR  128
#define OUT_COLS 198   // 64 + 3 + 128 + 3

// IEEE-f32 -> uint key, order-preserving and BIJECTIVE:
// key-min == float-min, key-equality == bit-equality.
__device__ __forceinline__ unsigned fkey(float v) {
    unsigned b = __float_as_uint(v);
    return b ^ ((unsigned)((int)b >> 31) | 0x80000000u);
}
__device__ __forceinline__ float fdec(unsigned k) {
    unsigned b = (k & 0x80000000u) ? (k ^ 0x80000000u) : ~k;
    return __uint_as_float(b);
}

// ---------------------------------------------------------------------------
// Fused kernel, R22: 8 waves/SIMD scan (R21 post-mortem: the only lever that
// ever moved the scan was waves/SIMD — 2/SIMD=62.5us, 4/SIMD=~40us; all
// within-wave levers null x5). 1024 knn blocks x 128 points (M=2), LDS cut
// to 37.9KB by replacing the pval[] merge with ds_min_u32 on monotone keys
// -> 4 blocks/CU = 32 waves/CU. 1280-block grid backfills as copies drain.
//   Phase A: value-only min3 scan (key formula text identical since R3,
//     bit-exact across 17 passing rounds); per-wave slice min -> atomicMin
//     key into gmin[pt] (exact: min is order-free; key bijective).
//   Phase B: waves whose own key == gmin key do atomicMin(winw, w):
//     lowest slice wins = first occurrence (slices ascending).
//   Phase C: per-wave compact + rescue scan (verbatim R16/R17 machinery).
//   Phase D: phase-split gather of cols 67..197 for the block's 128 rows.
// Blocks [1024,1280): idx-independent copy (cols 0..66, zeros, batch; R14).
// ---------------------------------------------------------------------------
__global__ __launch_bounds__(512, 8) void fused_kernel(
    const float* __restrict__ pos_hr,   // [NB*NH, 3]
    const float* __restrict__ pos_lr,   // [NB*NL, 3]
    const float* __restrict__ x_hr,     // [NB*NH, 64]
    const float* __restrict__ x_lr,     // [NB*NL, 128]
    float* __restrict__ out)
{
    __shared__ float4   cand[NL];       // 32 KiB (x, y, z, 0.5*|p|^2)
    __shared__ unsigned gmin[128];      // 0.5 KiB global min KEY per point
    __shared__ int      winw[128];      // 0.5 KiB winning slice per point
    __shared__ short    plist[8][128];  //  2 KiB per-wave compacted points
    __shared__ float    phsx[128], phsy[128], phsz[128];  // 1.5 KiB staged ph
    __shared__ int      s_idx[128];     // 0.5 KiB final winner (global lr row)

    if (blockIdx.x < 1024) {
        // ----------------------------- knn role -----------------------------
        const int b  = blockIdx.x >> 7;     // 128 blocks per batch
        const int p0 = blockIdx.x << 7;     // first global point (128/block)
        const int w  = threadIdx.x >> 6;    // wave id = candidate slice [0,8)
        const int l  = threadIdx.x & 63;

        const float* pl = pos_lr + (size_t)b * NL * 3;
        for (int j = threadIdx.x; j < NL; j += 512) {
            float x = pl[j * 3 + 0];
            float y = pl[j * 3 + 1];
            float z = pl[j * 3 + 2];
            cand[j] = make_float4(x, y, z, 0.5f * ((x * x + y * y) + z * z));
        }
        if (threadIdx.x < 128) {
            gmin[threadIdx.x] = 0xFFFFFFFFu;
            winw[threadIdx.x] = 8;
        }

        // M=2 points per lane
        float phx[2], phy[2], phz[2];
#pragma unroll
        for (int m = 0; m < 2; ++m) {
            const int pt = p0 + (m << 6) + l;
            phx[m] = pos_hr[pt * 3 + 0];
            phy[m] = pos_hr[pt * 3 + 1];
            phz[m] = pos_hr[pt * 3 + 2];
        }
        if (w == 0) {                        // stage ph for the rescue phase
#pragma unroll
            for (int m = 0; m < 2; ++m) {
                const int ptl = (m << 6) + l;
                phsx[ptl] = phx[m]; phsy[ptl] = phy[m]; phsz[ptl] = phz[m];
            }
        }
        __syncthreads();

        // Phase A: value-only min3 scan over this wave's 256-cand slice
        float best[2];
        best[0] = 3.4e38f; best[1] = 3.4e38f;

        const int base = w << 8;            // slice start (batch-local)
#pragma unroll 4
        for (int j = 0; j < 256; j += 2) {
            const float4 c0 = cand[base + j];
            const float4 c1 = cand[base + j + 1];
#pragma unroll
            for (int m = 0; m < 2; ++m) {
                float d0 = fmaf(-phz[m], c0.z, fmaf(-phy[m], c0.y, fmaf(-phx[m], c0.x, c0.w)));
                float d1 = fmaf(-phz[m], c1.z, fmaf(-phy[m], c1.y, fmaf(-phx[m], c1.x, c1.w)));
                best[m] = fminf(fminf(d0, d1), best[m]);   // -> v_min3_f32
            }
        }

        unsigned key[2];
#pragma unroll
        for (int m = 0; m < 2; ++m) {
            key[m] = fkey(best[m]);
            atomicMin(&gmin[(m << 6) + l], key[m]);        // exact min merge
        }
        __syncthreads();

        // Phase B: winner slice = lowest w whose key equals the global min
#pragma unroll
        for (int m = 0; m < 2; ++m) {
            const int pt = (m << 6) + l;
            if (key[m] == gmin[pt]) atomicMin(&winw[pt], w);
        }
        __syncthreads();

        // Phase C: compact points this wave won, then index-rescue scan
        int cnt = 0;
#pragma unroll
        for (int m = 0; m < 2; ++m) {
            const int pt = (m << 6) + l;
            const bool pred = (winw[pt] == w);
            const unsigned long long mask = __ballot(pred);
            const int pos = __popcll(mask & ((1ull << l) - 1ull));
            if (pred) plist[w][cnt + pos] = (short)pt;
            cnt += __popcll(mask);
        }

        for (int i = 0; i < cnt; ++i) {
            const int pt = plist[w][i];
            const float qx = phsx[pt], qy = phsy[pt], qz = phsz[pt];
            const float g  = fdec(gmin[pt]);
            int loc = 4;
#pragma unroll
            for (int k = 3; k >= 0; --k) {      // descending: final loc = lowest k
                const float4 c = cand[base + (l << 2) + k];
                const float d = fmaf(-qz, c.z, fmaf(-qy, c.y, fmaf(-qx, c.x, c.w)));
                if (d == g) loc = k;            // bit-exact recompute
            }
            const unsigned long long mk = __ballot(loc < 4);
            if (mk) {
                const int firstlane = __ffsll((unsigned long long)mk) - 1;
                const int locf = __shfl(loc, firstlane);
                if (l == 0)
                    s_idx[pt] = b * NL + base + (firstlane << 2) + locf;
            }
        }
        __syncthreads();

        // Phase D: gather cols 67..197 for rows p0..p0+127.
        // 128*131 = 16768 elems, stride 512: 5 batches of 6 (30) + 3 singles.
        // Decode: 512 = 3*131 + 119.
        {
            const int tid = threadIdx.x;
            int rl = tid / 131;
            int c  = tid - rl * 131;
            for (int t = 0; t < 5; ++t) {
                int rs[6], cs[6], ls[6];
                float vs[6];
#pragma unroll
                for (int k = 0; k < 6; ++k) {
                    rs[k] = rl; cs[k] = c;
                    ls[k] = s_idx[rl];
                    c += 119;
                    const int carry = (c >= 131) ? 1 : 0;
                    c -= carry ? 131 : 0;
                    rl += 3 + carry;
                }
#pragma unroll
                for (int k = 0; k < 6; ++k) {
                    const int cc = cs[k];
                    const float* a = (cc < F_LR) ? x_lr   + ls[k] * F_LR + cc
                                                 : pos_lr + ls[k] * 3    + (cc - F_LR);
                    vs[k] = *a;
                }
#pragma unroll
                for (int k = 0; k < 6; ++k) {
                    out[(size_t)(p0 + rs[k]) * OUT_COLS + 67 + cs[k]] = vs[k];
                }
            }
            // 3 guarded singles: e = tid + (30+s)*512, valid while e < 16768
#pragma unroll
            for (int s = 0; s < 3; ++s) {
                const int e = tid + (30 + s) * 512;
                if (e < 128 * 131) {
                    const int ll = s_idx[rl];
                    const float v = (c < F_LR) ? x_lr[ll * F_LR + c]
                                               : pos_lr[ll * 3 + (c - F_LR)];
                    out[(size_t)(p0 + rl) * OUT_COLS + 67 + c] = v;
                    c += 119;
                    const int carry = (c >= 131) ? 1 : 0;
                    c -= carry ? 131 : 0;
                    rl += 3 + carry;
                }
            }
        }
    } else {
        // ----------------------------- copy role ----------------------------
        const int cb = blockIdx.x - 1024;   // [0,256)
        const int r0 = cb << 9;             // 512 rows per block

#pragma unroll 4
        for (int e = threadIdx.x; e < 512 * 67; e += 512) {
            const int rl  = e / 67;
            const int c   = e - rl * 67;
            const int row = r0 + rl;
            const float v = (c < F_HR) ? x_hr[(row << 6) + c]
                                       : pos_hr[row * 3 + (c - F_HR)];
            out[row * OUT_COLS + c] = v;
        }

        const int R0 = NB * NH * OUT_COLS;  // 25,952,256
        const int Z  = NB * NH * 3;         // 393,216
        const int z0 = cb << 11;
#pragma unroll
        for (int e = threadIdx.x; e < 2048; e += 512) {
            const int i = z0 + e;
            out[R0 + i] = (i < Z) ? 0.0f : (float)((i - Z) >> 14);  // NH = 2^14
        }
    }
}

extern "C" void kernel_launch(void* const* d_in, const int* in_sizes, int n_in,
                              void* d_out, int out_size, void* d_ws, size_t ws_size,
                              hipStream_t stream) {
    const float* x_hr   = (const float*)d_in[0];
    const float* pos_hr = (const float*)d_in[1];
    // d_in[2] = batch_hr (int32) — unused, batch is contiguous repeats
    const float* x_lr   = (const float*)d_in[3];
    const float* pos_lr = (const float*)d_in[4];
    // d_in[5] = batch_lr (int32) — unused

    fused_kernel<<<dim3(1280), dim3(512), 0, stream>>>(
        pos_hr, pos_lr, x_hr, x_lr, (float*)d_out);
}